// Round 3
// baseline (16809.442 us; speedup 1.0000x reference)
//
#include <hip/hip_runtime.h>
#include <math.h>

#define KC 32
#define HD 64
#define OB 32
#define TLEN 500
#define NB 32
#define NT 256
#define LOG2PI 1.8378770664093453f

// ws layout (floats). First 64 floats (256 B) are memset to 0 by host:
//   [0..31]  flags (one per block)
#define WS_LW0 64
#define WS_LW1 96
#define WS_MU0 128
#define WS_MU1 2176
#define WS_PPB 4224   // bf16 PP region: 2 buffers x 131072 ushorts

typedef unsigned long long ull;

__device__ __forceinline__ unsigned bfp(float x){
  unsigned u = __float_as_uint(x);
  return (u + 0x7FFFu + ((u >> 16) & 1u)) >> 16;   // RNE bf16
}
__device__ __forceinline__ unsigned packbf(float a, float b){
  return bfp(a) | (bfp(b) << 16);
}
__device__ __forceinline__ float lo16(unsigned u){ return __uint_as_float(u << 16); }
__device__ __forceinline__ float hi16(unsigned u){ return __uint_as_float(u & 0xFFFF0000u); }

// device-coherent (agent-scope) accesses: no cache-flush fences needed
__device__ __forceinline__ ull ald64(const ull* p){
  return __hip_atomic_load(p, __ATOMIC_RELAXED, __HIP_MEMORY_SCOPE_AGENT);
}
__device__ __forceinline__ void ast64(ull* p, ull v){
  __hip_atomic_store(p, v, __ATOMIC_RELAXED, __HIP_MEMORY_SCOPE_AGENT);
}
__device__ __forceinline__ unsigned ald32(const unsigned* p){
  return __hip_atomic_load(p, __ATOMIC_RELAXED, __HIP_MEMORY_SCOPE_AGENT);
}
__device__ __forceinline__ void ast32(unsigned* p, unsigned v){
  __hip_atomic_store(p, v, __ATOMIC_RELAXED, __HIP_MEMORY_SCOPE_AGENT);
}

__global__ __launch_bounds__(NT, 1) void slds_kernel(
    const float* __restrict__ gdata, const float* __restrict__ gtl,
    const float* __restrict__ gA, const float* __restrict__ gltn,
    const float* __restrict__ gC, const float* __restrict__ glon,
    float* __restrict__ gout, float* __restrict__ ws)
{
  __shared__ __align__(16) float At[4096];    // At[g*64+r] = A[r][g]
  __shared__ __align__(16) float Ct[2048];    // Ct[d*64+h] = C[h][d]
  __shared__ __align__(16) float Cn[64*33];   // Cn[h*33+d] = C[h][d] (padded)
  __shared__ __align__(16) float Pm[64*68];
  __shared__ __align__(16) float Sc[64*68];
  __shared__ __align__(16) float WL[64*5 + 4]; // W rows, stride 5
  __shared__ __align__(16) float mbp[256];     // mubar partials [wave][64]
  __shared__ __align__(16) float mubar[64];
  __shared__ __align__(16) float muL[64];
  __shared__ float tl[32], lwb[32], qd[64], rdv[32], yv[32];
  __shared__ float Gbuf[16], cmPb[16];

  const int j = blockIdx.x, tid = threadIdx.x;
  unsigned* flags = (unsigned*)ws;
  unsigned short* ppb = (unsigned short*)(ws + WS_PPB);

  // ---- one-time init ----
  for (int e = tid; e < 4096; e += NT) { int r = e >> 6, g = e & 63; At[g*64 + r] = gA[j*4096 + e]; }
  for (int e = tid; e < 2048; e += NT) { int hh = e >> 5, dd = e & 31; Ct[dd*64 + hh] = gC[e]; Cn[hh*33 + dd] = gC[e]; }
  if (tid < 64) qd[tid] = expf(gltn[tid]);
  if (tid < 32) rdv[tid] = expf(glon[tid]);
  if (tid < 32) {
    float mx = -1e30f;
    for (int i = 0; i < 32; ++i) mx = fmaxf(mx, gtl[tid*32 + i]);
    float s = 0.f;
    for (int i = 0; i < 32; ++i) s += expf(gtl[tid*32 + i] - mx);
    tl[tid] = gtl[tid*32 + j] - (mx + logf(s));   // trans_log[k][j]
  }
  __syncthreads();

  const int h  = tid >> 2, gq = tid & 3;                 // row / col-quarter map
  const int r0 = (tid >> 4) << 2, c0 = (tid & 15) << 2;  // GEMM tile map
  const int km = tid >> 3, seg = tid & 7;                // mubar load map

  #pragma unroll 1
  for (int t = 0; t < TLEN; ++t) {
    float4 Preg[4];
    float mu_h = 0.f, base_lw;
    float llacc = 0.f;

    if (t == 0) {
      if (tid < 32) yv[tid] = gdata[tid];
      if (tid < 64) muL[tid] = 0.f;
      #pragma unroll
      for (int u = 0; u < 4; ++u) {
        int gb = gq*16 + 4*u;
        float4 vv = make_float4(0.f,0.f,0.f,0.f);
        if (h == gb  ) vv.x = 1.f;
        if (h == gb+1) vv.y = 1.f;
        if (h == gb+2) vv.z = 1.f;
        if (h == gb+3) vv.w = 1.f;
        Preg[u] = vv;                                // P = I
      }
      base_lw = tl[0];
      __syncthreads();
    } else {
      const unsigned* lwR = (const unsigned*)(ws + ((t & 1) ? WS_LW0 : WS_LW1));
      const ull* muR = (const ull*)(ws + ((t & 1) ? WS_MU0 : WS_MU1));
      const ull* pp8 = (const ull*)(ppb + ((t & 1) ? 0u : 131072u));

      // ---- flag barrier: wait for all blocks to have published step t-1 ----
      if (tid < 32) {
        while (ald32(&flags[tid]) < (unsigned)t) __builtin_amdgcn_s_sleep(1);
        // fold lw read + tl add into the poll wave, broadcast via LDS
        lwb[tid] = tl[tid] + __uint_as_float(ald32(lwR + tid));
        yv[tid] = gdata[t*32 + tid];
      }
      __syncthreads();

      // early mu loads (coherent; in flight during weight computation)
      const ull* mup = muR + ((size_t)km*64 + seg*8) / 2;
      ull mq0 = ald64(mup), mq1 = ald64(mup+1), mq2 = ald64(mup+2), mq3 = ald64(mup+3);

      // --- r weights (redundant per thread; lwb is LDS broadcast) ---
      float av[32];
      #pragma unroll
      for (int k = 0; k < 32; ++k) av[k] = lwb[k];
      float mx = av[0];
      #pragma unroll
      for (int k = 1; k < 32; ++k) mx = fmaxf(mx, av[k]);

      // --- PP prefetch (8-deep rotating, coherent 8B loads) ---
      const int qb = tid * 4;
      ull qa[8][4];
      #pragma unroll
      for (int p = 0; p < 8; ++p) {
        #pragma unroll
        for (int q = 0; q < 4; ++q) qa[p][q] = ald64(pp8 + p*1024 + qb + q);
      }

      float ssum = 0.f;
      #pragma unroll
      for (int k = 0; k < 32; ++k) { av[k] = expf(av[k] - mx); ssum += av[k]; }
      float inv = 1.f / ssum;
      base_lw = mx + logf(ssum);

      // --- mix: acc = sum_k r_k PP_k  (thread owns row h, cols gq*16..+16) ---
      float4 acc[4];
      #pragma unroll
      for (int u = 0; u < 4; ++u) acc[u] = make_float4(0.f,0.f,0.f,0.f);
      #pragma unroll
      for (int k = 0; k < 32; ++k) {
        ull q0 = qa[k&7][0], q1 = qa[k&7][1], q2 = qa[k&7][2], q3 = qa[k&7][3];
        if (k < 24) {
          #pragma unroll
          for (int q = 0; q < 4; ++q) qa[k&7][q] = ald64(pp8 + (k+8)*1024 + qb + q);
        }
        float rk = av[k] * inv;
        unsigned a0 = (unsigned)q0, a1 = (unsigned)(q0 >> 32);
        unsigned b0 = (unsigned)q1, b1 = (unsigned)(q1 >> 32);
        unsigned c0_ = (unsigned)q2, c1 = (unsigned)(q2 >> 32);
        unsigned d0_ = (unsigned)q3, d1 = (unsigned)(q3 >> 32);
        acc[0].x += rk*lo16(a0); acc[0].y += rk*hi16(a0);
        acc[0].z += rk*lo16(a1); acc[0].w += rk*hi16(a1);
        acc[1].x += rk*lo16(b0); acc[1].y += rk*hi16(b0);
        acc[1].z += rk*lo16(b1); acc[1].w += rk*hi16(b1);
        acc[2].x += rk*lo16(c0_); acc[2].y += rk*hi16(c0_);
        acc[2].z += rk*lo16(c1); acc[2].w += rk*hi16(c1);
        acc[3].x += rk*lo16(d0_); acc[3].y += rk*hi16(d0_);
        acc[3].z += rk*lo16(d1); acc[3].w += rk*hi16(d1);
      }

      // --- mubar partials: scale early-loaded mu by r_k, reduce over k ---
      {
        float rk2 = av[km] * inv;
        float4 m0 = make_float4(__uint_as_float((unsigned)mq0), __uint_as_float((unsigned)(mq0>>32)),
                                __uint_as_float((unsigned)mq1), __uint_as_float((unsigned)(mq1>>32)));
        float4 m1 = make_float4(__uint_as_float((unsigned)mq2), __uint_as_float((unsigned)(mq2>>32)),
                                __uint_as_float((unsigned)mq3), __uint_as_float((unsigned)(mq3>>32)));
        m0.x *= rk2; m0.y *= rk2; m0.z *= rk2; m0.w *= rk2;
        m1.x *= rk2; m1.y *= rk2; m1.z *= rk2; m1.w *= rk2;
        #pragma unroll
        for (int mk = 8; mk < 64; mk <<= 1) {
          m0.x += __shfl_xor(m0.x, mk); m0.y += __shfl_xor(m0.y, mk);
          m0.z += __shfl_xor(m0.z, mk); m0.w += __shfl_xor(m0.w, mk);
          m1.x += __shfl_xor(m1.x, mk); m1.y += __shfl_xor(m1.y, mk);
          m1.z += __shfl_xor(m1.z, mk); m1.w += __shfl_xor(m1.w, mk);
        }
        if ((tid & 56) == 0) {
          int w = tid >> 6;
          *(float4*)&mbp[w*64 + seg*8]     = m0;
          *(float4*)&mbp[w*64 + seg*8 + 4] = m1;
        }
      }
      __syncthreads();
      if (tid < 64) mubar[tid] = mbp[tid] + mbp[64+tid] + mbp[128+tid] + mbp[192+tid];
      __syncthreads();

      // --- M = acc - mubar mubar^T -> Pm ; mu_pred = A mubar ---
      {
        float mh_ = mubar[h];
        #pragma unroll
        for (int u = 0; u < 4; ++u) {
          float4 mc = *(const float4*)&mubar[gq*16 + u*4];
          acc[u].x -= mh_*mc.x; acc[u].y -= mh_*mc.y;
          acc[u].z -= mh_*mc.z; acc[u].w -= mh_*mc.w;
          *(float4*)&Pm[h*68 + gq*16 + u*4] = acc[u];
        }
        float mp = 0.f;
        #pragma unroll
        for (int i = 0; i < 16; ++i) { int g = gq*16 + i; mp += At[g*64 + h] * mubar[g]; }
        mp += __shfl_xor(mp, 1); mp += __shfl_xor(mp, 2);
        mu_h = mp;   // valid on all lanes
      }
      __syncthreads();

      // --- GEMM1: AP = A*M, stored transposed into Sc ---
      {
        float gacc[4][4] = {};
        for (int g = 0; g < 64; ++g) {
          float4 a = *(const float4*)&At[g*64 + r0];
          float4 b = *(const float4*)&Pm[g*68 + c0];
          float avv[4] = {a.x,a.y,a.z,a.w};
          float bvv[4] = {b.x,b.y,b.z,b.w};
          #pragma unroll
          for (int ii = 0; ii < 4; ++ii)
            #pragma unroll
            for (int jj = 0; jj < 4; ++jj) gacc[ii][jj] += avv[ii]*bvv[jj];
        }
        #pragma unroll
        for (int jj = 0; jj < 4; ++jj) {
          float4 col = make_float4(gacc[0][jj], gacc[1][jj], gacc[2][jj], gacc[3][jj]);
          *(float4*)&Sc[(c0+jj)*68 + r0] = col;
        }
      }
      __syncthreads();

      // --- GEMM2: P = A*AP^T (+ Q diag) -> Pm ---
      {
        float gacc[4][4] = {};
        for (int g = 0; g < 64; ++g) {
          float4 a = *(const float4*)&At[g*64 + r0];
          float4 b = *(const float4*)&Sc[g*68 + c0];
          float avv[4] = {a.x,a.y,a.z,a.w};
          float bvv[4] = {b.x,b.y,b.z,b.w};
          #pragma unroll
          for (int ii = 0; ii < 4; ++ii)
            #pragma unroll
            for (int jj = 0; jj < 4; ++jj) gacc[ii][jj] += avv[ii]*bvv[jj];
        }
        if (r0 == c0) {
          gacc[0][0] += qd[r0]; gacc[1][1] += qd[r0+1];
          gacc[2][2] += qd[r0+2]; gacc[3][3] += qd[r0+3];
        }
        #pragma unroll
        for (int ii = 0; ii < 4; ++ii)
          *(float4*)&Pm[(r0+ii)*68 + c0] = make_float4(gacc[ii][0], gacc[ii][1], gacc[ii][2], gacc[ii][3]);
      }
      if (gq == 0) muL[h] = mu_h;
      __syncthreads();

      #pragma unroll
      for (int u = 0; u < 4; ++u) Preg[u] = *(const float4*)&Pm[h*68 + gq*16 + 4*u];
    }

    // ---- observation update: 8 rounds of exact rank-4 block Kalman ----
    #pragma unroll 1
    for (int rnd = 0; rnd < 8; ++rnd) {
      const int d0 = rnd * 4;
      float wv[4];
      #pragma unroll
      for (int i = 0; i < 4; ++i) {
        const float4* cc = (const float4*)&Ct[(d0+i)*64 + gq*16];
        float wi = 0.f;
        #pragma unroll
        for (int u = 0; u < 4; ++u) {
          float4 c4 = cc[u]; float4 p = Preg[u];
          wi += p.x*c4.x + p.y*c4.y + p.z*c4.z + p.w*c4.w;
        }
        wv[i] = wi;
      }
      #pragma unroll
      for (int i = 0; i < 4; ++i) { wv[i] += __shfl_xor(wv[i], 1); wv[i] += __shfl_xor(wv[i], 2); }
      if (gq == 0) {
        WL[h*5+0]=wv[0]; WL[h*5+1]=wv[1]; WL[h*5+2]=wv[2]; WL[h*5+3]=wv[3];
      }
      {
        float cmp_ = Cn[h*33 + d0 + gq] * muL[h];
        cmp_ += __shfl_xor(cmp_, 4); cmp_ += __shfl_xor(cmp_, 8);
        cmp_ += __shfl_xor(cmp_, 16); cmp_ += __shfl_xor(cmp_, 32);
        if ((tid & 60) == 0) cmPb[(tid >> 6)*4 + gq] = cmp_;
      }
      __syncthreads();

      if (tid < 64) {
        int q = tid >> 4, ii = (tid >> 2) & 3, jj = tid & 3;
        float g_ = 0.f;
        #pragma unroll
        for (int hh = 0; hh < 16; ++hh) {
          int hq = q*16 + hh;
          g_ += Cn[hq*33 + d0 + ii] * WL[hq*5 + jj];
        }
        g_ += __shfl_xor(g_, 16); g_ += __shfl_xor(g_, 32);
        if (tid < 16) Gbuf[tid] = g_;
      }
      __syncthreads();

      {
        float G10=Gbuf[4],  G20=Gbuf[8],  G21=Gbuf[9];
        float G30=Gbuf[12], G31=Gbuf[13], G32=Gbuf[14];
        float s00=Gbuf[0]+rdv[d0],  s11=Gbuf[5]+rdv[d0+1];
        float s22=Gbuf[10]+rdv[d0+2], s33=Gbuf[15]+rdv[d0+3];
        float cm0=cmPb[0]+cmPb[4]+cmPb[8]+cmPb[12];
        float cm1=cmPb[1]+cmPb[5]+cmPb[9]+cmPb[13];
        float cm2=cmPb[2]+cmPb[6]+cmPb[10]+cmPb[14];
        float cm3=cmPb[3]+cmPb[7]+cmPb[11]+cmPb[15];
        float v0_=yv[d0]-cm0, v1_=yv[d0+1]-cm1, v2_=yv[d0+2]-cm2, v3_=yv[d0+3]-cm3;

        float L00=sqrtf(s00), rr0=1.f/L00;
        float L10=G10*rr0, L20=G20*rr0, L30=G30*rr0;
        float L11=sqrtf(s11-L10*L10), rr1=1.f/L11;
        float L21=(G21-L20*L10)*rr1, L31=(G31-L30*L10)*rr1;
        float L22=sqrtf(s22-L20*L20-L21*L21), rr2=1.f/L22;
        float L32=(G32-L30*L20-L31*L21)*rr2;
        float L33=sqrtf(s33-L30*L30-L31*L31-L32*L32), rr3=1.f/L33;
        llacc += 2.f*logf(L00*L11*L22*L33);

        float m00=rr0, m11=rr1, m22=rr2, m33=rr3;
        float m10=-rr1*(L10*m00);
        float m20=-rr2*(L20*m00+L21*m10);
        float m21=-rr2*(L21*m11);
        float m30=-rr3*(L30*m00+L31*m10+L32*m20);
        float m31=-rr3*(L31*m11+L32*m21);
        float m32=-rr3*(L32*m22);

        float si00=m00*m00+m10*m10+m20*m20+m30*m30;
        float si01=m10*m11+m20*m21+m30*m31;
        float si02=m20*m22+m30*m32;
        float si03=m30*m33;
        float si11=m11*m11+m21*m21+m31*m31;
        float si12=m21*m22+m31*m32;
        float si13=m31*m33;
        float si22=m22*m22+m32*m32;
        float si23=m32*m33;
        float si33=m33*m33;

        float uu0=si00*v0_+si01*v1_+si02*v2_+si03*v3_;
        float uu1=si01*v0_+si11*v1_+si12*v2_+si13*v3_;
        float uu2=si02*v0_+si12*v1_+si22*v2_+si23*v3_;
        float uu3=si03*v0_+si13*v1_+si23*v2_+si33*v3_;
        llacc += v0_*uu0 + v1_*uu1 + v2_*uu2 + v3_*uu3;

        float wr0=wv[0], wr1=wv[1], wr2=wv[2], wr3=wv[3];
        float zr0=wr0*si00+wr1*si01+wr2*si02+wr3*si03;
        float zr1=wr0*si01+wr1*si11+wr2*si12+wr3*si13;
        float zr2=wr0*si02+wr1*si12+wr2*si22+wr3*si23;
        float zr3=wr0*si03+wr1*si13+wr2*si23+wr3*si33;

        #pragma unroll
        for (int u = 0; u < 4; ++u) {
          int gb = gq*16 + u*4;
          Preg[u].x -= zr0*WL[(gb+0)*5+0]+zr1*WL[(gb+0)*5+1]+zr2*WL[(gb+0)*5+2]+zr3*WL[(gb+0)*5+3];
          Preg[u].y -= zr0*WL[(gb+1)*5+0]+zr1*WL[(gb+1)*5+1]+zr2*WL[(gb+1)*5+2]+zr3*WL[(gb+1)*5+3];
          Preg[u].z -= zr0*WL[(gb+2)*5+0]+zr1*WL[(gb+2)*5+1]+zr2*WL[(gb+2)*5+2]+zr3*WL[(gb+2)*5+3];
          Preg[u].w -= zr0*WL[(gb+3)*5+0]+zr1*WL[(gb+3)*5+1]+zr2*WL[(gb+3)*5+2]+zr3*WL[(gb+3)*5+3];
        }
        mu_h += wr0*uu0 + wr1*uu1 + wr2*uu2 + wr3*uu3;
        if (gq == 0) muL[h] = mu_h;
      }
      __syncthreads();
    }
    float lw_j = base_lw - 0.5f * (OB * LOG2PI + llacc);

    // ---- write state (coherent): PPbf16 = 0.5(P+P^T) + mu mu^T ; mu ; lw ----
    #pragma unroll
    for (int u = 0; u < 4; ++u) *(float4*)&Pm[h*68 + gq*16 + 4*u] = Preg[u];
    __syncthreads();
    {
      unsigned* lwW = (unsigned*)(ws + ((t & 1) ? WS_LW1 : WS_LW0));
      unsigned* muW = (unsigned*)(ws + ((t & 1) ? WS_MU1 : WS_MU0));
      ull* ppW = (ull*)(ppb + ((t & 1) ? 131072u : 0u)) + (size_t)j*1024 + tid*4;
      float mh = muL[h];
      unsigned pk[8];
      #pragma unroll
      for (int u = 0; u < 4; ++u) {
        int gb = gq*16 + 4*u;
        float4 pv = Preg[u];
        float4 pt = make_float4(Pm[(gb+0)*68 + h], Pm[(gb+1)*68 + h],
                                Pm[(gb+2)*68 + h], Pm[(gb+3)*68 + h]);
        float4 m4 = *(const float4*)&muL[gb];
        float ox = 0.5f*(pv.x + pt.x) + mh*m4.x;
        float oy = 0.5f*(pv.y + pt.y) + mh*m4.y;
        float oz = 0.5f*(pv.z + pt.z) + mh*m4.z;
        float ow = 0.5f*(pv.w + pt.w) + mh*m4.w;
        pk[u*2]   = packbf(ox, oy);
        pk[u*2+1] = packbf(oz, ow);
      }
      ast64(ppW+0, (ull)pk[0] | ((ull)pk[1] << 32));
      ast64(ppW+1, (ull)pk[2] | ((ull)pk[3] << 32));
      ast64(ppW+2, (ull)pk[4] | ((ull)pk[5] << 32));
      ast64(ppW+3, (ull)pk[6] | ((ull)pk[7] << 32));
      if (gq == 0) ast32(&muW[j*64 + h], __float_as_uint(mu_h));
      if (tid == 0) ast32(&lwW[j], __float_as_uint(lw_j));
    }
    // publish: all stores drained, then set flag (same-wave order: store < polls)
    asm volatile("s_waitcnt vmcnt(0)" ::: "memory");
    __syncthreads();
    if (tid == 0) ast32(&flags[j], (unsigned)(t + 1));
  }

  // ---- final logsumexp over components (block 0) ----
  if (j == 0) {
    if (tid < 32) {
      while (ald32(&flags[tid]) < (unsigned)TLEN) __builtin_amdgcn_s_sleep(1);
    }
    __syncthreads();
    if (tid == 0) {
      const unsigned* lw = (const unsigned*)(ws + (((TLEN - 1) & 1) ? WS_LW1 : WS_LW0));
      float mx = -1e30f;
      float v[KC];
      for (int k = 0; k < KC; ++k) { v[k] = __uint_as_float(ald32(lw + k)); mx = fmaxf(mx, v[k]); }
      float s = 0.f;
      for (int k = 0; k < KC; ++k) s += expf(v[k] - mx);
      gout[0] = mx + logf(s);
    }
  }
}

extern "C" void kernel_launch(void* const* d_in, const int* in_sizes, int n_in,
                              void* d_out, int out_size, void* d_ws, size_t ws_size,
                              hipStream_t stream) {
  const float* gdata = (const float*)d_in[0];
  const float* gtl   = (const float*)d_in[1];
  const float* gA    = (const float*)d_in[2];
  const float* gltn  = (const float*)d_in[3];
  const float* gC    = (const float*)d_in[4];
  const float* glon  = (const float*)d_in[5];
  float* ws = (float*)d_ws;

  hipMemsetAsync(d_ws, 0, 256, stream);
  hipLaunchKernelGGL(slds_kernel, dim3(NB), dim3(NT), 0, stream,
                     gdata, gtl, gA, gltn, gC, glon, (float*)d_out, ws);
}

// Round 4
// 16235.089 us; speedup vs baseline: 1.0354x; 1.0354x over previous
//
#include <hip/hip_runtime.h>
#include <math.h>

#define KC 32
#define HD 64
#define OB 32
#define TLEN 500
#define NB 32
#define NT 256
#define LOG2PI 1.8378770664093453f
#define PIT 72   // bf16 LDS row pitch (pad 64->72 kills bank conflicts on b128 reads)

// ws layout (floats). First 64 floats (256 B) memset to 0 by host: flags[32]
#define WS_LW0 64
#define WS_LW1 96
#define WS_MU0 128
#define WS_MU1 2176
#define WS_PPB 4224   // bf16 PP region: 2 buffers x 131072 ushorts

typedef unsigned long long ull;
typedef __attribute__((ext_vector_type(8))) short short8;
typedef __attribute__((ext_vector_type(4))) float f32x4;

__device__ __forceinline__ unsigned bfp(float x){
  unsigned u = __float_as_uint(x);
  return (u + 0x7FFFu + ((u >> 16) & 1u)) >> 16;   // RNE bf16
}
__device__ __forceinline__ unsigned packbf(float a, float b){
  return bfp(a) | (bfp(b) << 16);
}
__device__ __forceinline__ float lo16(unsigned u){ return __uint_as_float(u << 16); }
__device__ __forceinline__ float hi16(unsigned u){ return __uint_as_float(u & 0xFFFF0000u); }

__device__ __forceinline__ ull ald64(const ull* p){
  return __hip_atomic_load(p, __ATOMIC_RELAXED, __HIP_MEMORY_SCOPE_AGENT);
}
__device__ __forceinline__ void ast64(ull* p, ull v){
  __hip_atomic_store(p, v, __ATOMIC_RELAXED, __HIP_MEMORY_SCOPE_AGENT);
}
__device__ __forceinline__ unsigned ald32(const unsigned* p){
  return __hip_atomic_load(p, __ATOMIC_RELAXED, __HIP_MEMORY_SCOPE_AGENT);
}
__device__ __forceinline__ void ast32(unsigned* p, unsigned v){
  __hip_atomic_store(p, v, __ATOMIC_RELAXED, __HIP_MEMORY_SCOPE_AGENT);
}

__global__ __launch_bounds__(NT, 1) void slds_kernel(
    const float* __restrict__ gdata, const float* __restrict__ gtl,
    const float* __restrict__ gA, const float* __restrict__ gltn,
    const float* __restrict__ gC, const float* __restrict__ glon,
    float* __restrict__ gout, float* __restrict__ ws)
{
  __shared__ __align__(16) float At[4096];              // At[g*64+r] = A[r][g] (fp32, mu_pred)
  __shared__ __align__(16) unsigned short Abf[64*PIT];  // A row-major bf16
  __shared__ __align__(16) float Ct[2048];              // Ct[d*64+h] = C[h][d]
  __shared__ __align__(16) float Cn[64*33];             // Cn[h*33+d] = C[h][d]
  __shared__ __align__(16) float Pm[64*68];             // fp32 P buffer (stride 68)
  __shared__ __align__(16) unsigned short Mbf[64*PIT];  // M bf16 (symmetric)
  __shared__ __align__(16) unsigned short Tbf[64*PIT];  // T = A*M bf16
  __shared__ __align__(16) float WL[64*5 + 4];
  __shared__ __align__(16) float mbp[256];
  __shared__ __align__(16) float mubar[64];
  __shared__ __align__(16) float muL[64];
  __shared__ float tl[32], rw[32], qd[64], rdv[32], yv[32], bl[1];

  const int j = blockIdx.x, tid = threadIdx.x;
  unsigned* flags = (unsigned*)ws;
  unsigned short* ppb = (unsigned short*)(ws + WS_PPB);

  // ---- one-time init ----
  for (int e = tid; e < 4096; e += NT) {
    int r = e >> 6, g = e & 63;
    float a = gA[j*4096 + e];
    At[g*64 + r] = a;
    Abf[r*PIT + g] = (unsigned short)bfp(a);
  }
  for (int e = tid; e < 2048; e += NT) { int hh = e >> 5, dd = e & 31; Ct[dd*64 + hh] = gC[e]; Cn[hh*33 + dd] = gC[e]; }
  if (tid < 64) qd[tid] = expf(gltn[tid]);
  if (tid < 32) rdv[tid] = expf(glon[tid]);
  if (tid < 32) {
    float mx = -1e30f;
    for (int i = 0; i < 32; ++i) mx = fmaxf(mx, gtl[tid*32 + i]);
    float s = 0.f;
    for (int i = 0; i < 32; ++i) s += expf(gtl[tid*32 + i] - mx);
    tl[tid] = gtl[tid*32 + j] - (mx + logf(s));   // trans_log[k][j]
  }
  __syncthreads();

  const int h  = tid >> 2, gq = tid & 3;       // row / col-quarter map
  const int km = tid >> 3, seg = tid & 7;      // mubar load map
  const int wid = tid >> 6, l = tid & 63;      // wave id / lane
  const int lr = l & 15, lk = l >> 4;          // mfma row-in-tile / k-group

  #pragma unroll 1
  for (int t = 0; t < TLEN; ++t) {
    float4 Preg[4];
    float mu_h = 0.f, base_lw;
    float llacc = 0.f;

    if (t == 0) {
      if (tid < 32) yv[tid] = gdata[tid];
      if (tid < 64) muL[tid] = 0.f;
      #pragma unroll
      for (int u = 0; u < 4; ++u) {
        int gb = gq*16 + 4*u;
        float4 vv = make_float4(0.f,0.f,0.f,0.f);
        if (h == gb  ) vv.x = 1.f;
        if (h == gb+1) vv.y = 1.f;
        if (h == gb+2) vv.z = 1.f;
        if (h == gb+3) vv.w = 1.f;
        Preg[u] = vv;                                // P = I
      }
      base_lw = tl[0];
      __syncthreads();
    } else {
      const unsigned* lwR = (const unsigned*)(ws + ((t & 1) ? WS_LW0 : WS_LW1));
      const ull* muR = (const ull*)(ws + ((t & 1) ? WS_MU0 : WS_MU1));
      const ull* pp8 = (const ull*)(ppb + ((t & 1) ? 0u : 131072u));

      // ---- flag barrier + weights on the poll wave (once, broadcast) ----
      if (tid < 32) {
        while (ald32(&flags[tid]) < (unsigned)t) __builtin_amdgcn_s_sleep(1);
        float a = tl[tid] + __uint_as_float(ald32(lwR + tid));
        float m = a;
        #pragma unroll
        for (int s = 1; s < 32; s <<= 1) m = fmaxf(m, __shfl_xor(m, s, 32));
        float e = expf(a - m);
        float ss = e;
        #pragma unroll
        for (int s = 1; s < 32; s <<= 1) ss += __shfl_xor(ss, s, 32);
        rw[tid] = e / ss;
        if (tid == 0) bl[0] = m + logf(ss);
        yv[tid] = gdata[t*32 + tid];
      }
      __syncthreads();
      base_lw = bl[0];

      // early mu loads (coherent; in flight during mix)
      const ull* mup = muR + ((size_t)km*64 + seg*8) / 2;
      ull mq0 = ald64(mup), mq1 = ald64(mup+1), mq2 = ald64(mup+2), mq3 = ald64(mup+3);

      // --- PP prefetch (8-deep rotating, coherent 8B loads) ---
      const int qb = tid * 4;
      ull qa[8][4];
      #pragma unroll
      for (int p = 0; p < 8; ++p) {
        #pragma unroll
        for (int q = 0; q < 4; ++q) qa[p][q] = ald64(pp8 + p*1024 + qb + q);
      }

      // --- mix: acc = sum_k r_k PP_k  (thread owns row h, cols gq*16..+16) ---
      float4 acc[4];
      #pragma unroll
      for (int u = 0; u < 4; ++u) acc[u] = make_float4(0.f,0.f,0.f,0.f);
      #pragma unroll
      for (int k = 0; k < 32; ++k) {
        ull q0 = qa[k&7][0], q1 = qa[k&7][1], q2 = qa[k&7][2], q3 = qa[k&7][3];
        if (k < 24) {
          #pragma unroll
          for (int q = 0; q < 4; ++q) qa[k&7][q] = ald64(pp8 + (k+8)*1024 + qb + q);
        }
        float rk = rw[k];
        unsigned a0 = (unsigned)q0, a1 = (unsigned)(q0 >> 32);
        unsigned b0 = (unsigned)q1, b1 = (unsigned)(q1 >> 32);
        unsigned c0_ = (unsigned)q2, c1 = (unsigned)(q2 >> 32);
        unsigned d0_ = (unsigned)q3, d1 = (unsigned)(q3 >> 32);
        acc[0].x += rk*lo16(a0); acc[0].y += rk*hi16(a0);
        acc[0].z += rk*lo16(a1); acc[0].w += rk*hi16(a1);
        acc[1].x += rk*lo16(b0); acc[1].y += rk*hi16(b0);
        acc[1].z += rk*lo16(b1); acc[1].w += rk*hi16(b1);
        acc[2].x += rk*lo16(c0_); acc[2].y += rk*hi16(c0_);
        acc[2].z += rk*lo16(c1); acc[2].w += rk*hi16(c1);
        acc[3].x += rk*lo16(d0_); acc[3].y += rk*hi16(d0_);
        acc[3].z += rk*lo16(d1); acc[3].w += rk*hi16(d1);
      }

      // --- mubar partials ---
      {
        float rk2 = rw[km];
        float4 m0 = make_float4(__uint_as_float((unsigned)mq0), __uint_as_float((unsigned)(mq0>>32)),
                                __uint_as_float((unsigned)mq1), __uint_as_float((unsigned)(mq1>>32)));
        float4 m1 = make_float4(__uint_as_float((unsigned)mq2), __uint_as_float((unsigned)(mq2>>32)),
                                __uint_as_float((unsigned)mq3), __uint_as_float((unsigned)(mq3>>32)));
        m0.x *= rk2; m0.y *= rk2; m0.z *= rk2; m0.w *= rk2;
        m1.x *= rk2; m1.y *= rk2; m1.z *= rk2; m1.w *= rk2;
        #pragma unroll
        for (int mk = 8; mk < 64; mk <<= 1) {
          m0.x += __shfl_xor(m0.x, mk); m0.y += __shfl_xor(m0.y, mk);
          m0.z += __shfl_xor(m0.z, mk); m0.w += __shfl_xor(m0.w, mk);
          m1.x += __shfl_xor(m1.x, mk); m1.y += __shfl_xor(m1.y, mk);
          m1.z += __shfl_xor(m1.z, mk); m1.w += __shfl_xor(m1.w, mk);
        }
        if ((tid & 56) == 0) {
          int w = tid >> 6;
          *(float4*)&mbp[w*64 + seg*8]     = m0;
          *(float4*)&mbp[w*64 + seg*8 + 4] = m1;
        }
      }
      __syncthreads();
      if (tid < 64) mubar[tid] = mbp[tid] + mbp[64+tid] + mbp[128+tid] + mbp[192+tid];
      __syncthreads();

      // --- M = acc - mubar mubar^T -> Mbf (bf16) ; mu_pred = A mubar ---
      {
        float mh_ = mubar[h];
        unsigned mp8[8];
        #pragma unroll
        for (int u = 0; u < 4; ++u) {
          float4 mc = *(const float4*)&mubar[gq*16 + u*4];
          acc[u].x -= mh_*mc.x; acc[u].y -= mh_*mc.y;
          acc[u].z -= mh_*mc.z; acc[u].w -= mh_*mc.w;
          mp8[u*2]   = packbf(acc[u].x, acc[u].y);
          mp8[u*2+1] = packbf(acc[u].z, acc[u].w);
        }
        *(uint4*)&Mbf[h*PIT + gq*16]     = make_uint4(mp8[0],mp8[1],mp8[2],mp8[3]);
        *(uint4*)&Mbf[h*PIT + gq*16 + 8] = make_uint4(mp8[4],mp8[5],mp8[6],mp8[7]);
        float mp = 0.f;
        #pragma unroll
        for (int i = 0; i < 16; ++i) { int g = gq*16 + i; mp += At[g*64 + h] * mubar[g]; }
        mp += __shfl_xor(mp, 1); mp += __shfl_xor(mp, 2);
        mu_h = mp;   // valid on all lanes
        if (gq == 0) muL[h] = mu_h;
      }
      __syncthreads();

      // --- MFMA predict: T = A*M ; P = T*A^T (+Q). Wave-local (tile-row wid). ---
      {
        const int ar = (wid*16 + lr)*PIT + lk*8;
        short8 af0 = *(const short8*)&Abf[ar];
        short8 af1 = *(const short8*)&Abf[ar + 32];
        #pragma unroll
        for (int tc = 0; tc < 4; ++tc) {
          const int br = (tc*16 + lr)*PIT + lk*8;
          short8 b0 = *(const short8*)&Mbf[br];        // M symmetric: row-gather = col-gather
          short8 b1 = *(const short8*)&Mbf[br + 32];
          f32x4 d = {0.f, 0.f, 0.f, 0.f};
          d = __builtin_amdgcn_mfma_f32_16x16x32_bf16(af0, b0, d, 0, 0, 0);
          d = __builtin_amdgcn_mfma_f32_16x16x32_bf16(af1, b1, d, 0, 0, 0);
          #pragma unroll
          for (int r = 0; r < 4; ++r)
            Tbf[(wid*16 + lk*4 + r)*PIT + tc*16 + lr] = (unsigned short)bfp(d[r]);
        }
        short8 t0 = *(const short8*)&Tbf[ar];
        short8 t1 = *(const short8*)&Tbf[ar + 32];
        #pragma unroll
        for (int tc = 0; tc < 4; ++tc) {
          const int br = (tc*16 + lr)*PIT + lk*8;
          short8 b0 = *(const short8*)&Abf[br];        // B = A^T: b_frag[i]=A[col][k]
          short8 b1 = *(const short8*)&Abf[br + 32];
          f32x4 d = {0.f, 0.f, 0.f, 0.f};
          d = __builtin_amdgcn_mfma_f32_16x16x32_bf16(t0, b0, d, 0, 0, 0);
          d = __builtin_amdgcn_mfma_f32_16x16x32_bf16(t1, b1, d, 0, 0, 0);
          #pragma unroll
          for (int r = 0; r < 4; ++r) {
            int grow = wid*16 + lk*4 + r, gcol = tc*16 + lr;
            Pm[grow*68 + gcol] = d[r] + (grow == gcol ? qd[grow] : 0.f);
          }
        }
      }
      // wave-local: rows h of Pm were written by this wave
      #pragma unroll
      for (int u = 0; u < 4; ++u) Preg[u] = *(const float4*)&Pm[h*68 + gq*16 + 4*u];
    }

    // ---- observation update: 8 rounds of exact rank-4 block Kalman ----
    #pragma unroll 1
    for (int rnd = 0; rnd < 8; ++rnd) {
      const int d0 = rnd * 4;
      // W = P C4 partials, reduce over gq
      float wvv[4];
      #pragma unroll
      for (int i = 0; i < 4; ++i) {
        const float4* cc = (const float4*)&Ct[(d0+i)*64 + gq*16];
        float wi = 0.f;
        #pragma unroll
        for (int u = 0; u < 4; ++u) {
          float4 c4 = cc[u]; float4 p = Preg[u];
          wi += p.x*c4.x + p.y*c4.y + p.z*c4.z + p.w*c4.w;
        }
        wvv[i] = wi;
      }
      #pragma unroll
      for (int i = 0; i < 4; ++i) { wvv[i] += __shfl_xor(wvv[i], 1); wvv[i] += __shfl_xor(wvv[i], 2); }
      if (gq == 0) { WL[h*5+0]=wvv[0]; WL[h*5+1]=wvv[1]; WL[h*5+2]=wvv[2]; WL[h*5+3]=wvv[3]; }
      // cm = C4^T mu, per-wave redundant (lane l owns g=l)
      float cm[4];
      {
        float mg = muL[l];
        #pragma unroll
        for (int i = 0; i < 4; ++i) cm[i] = Cn[l*33 + d0 + i] * mg;
        #pragma unroll
        for (int s = 1; s < 64; s <<= 1) {
          #pragma unroll
          for (int i = 0; i < 4; ++i) cm[i] += __shfl_xor(cm[i], s);
        }
      }
      __syncthreads();

      // per-wave Gram G = C4^T W (redundant per wave; no extra sync)
      float Gv[16];
      {
        int ii = (l >> 2) & 3, jj = l & 3;
        float g_ = 0.f;
        #pragma unroll
        for (int hh = 0; hh < 16; ++hh) {
          int hq = lk*16 + hh;
          g_ += Cn[hq*33 + d0 + ii] * WL[hq*5 + jj];
        }
        g_ += __shfl_xor(g_, 16); g_ += __shfl_xor(g_, 32);
        #pragma unroll
        for (int b = 0; b < 16; ++b) Gv[b] = __shfl(g_, (l & 48) | b);
      }

      // redundant per-thread 4x4 Cholesky + inverse, then rank-4 update
      {
        float G10=Gv[4],  G20=Gv[8],  G21=Gv[9];
        float G30=Gv[12], G31=Gv[13], G32=Gv[14];
        float s00=Gv[0]+rdv[d0],  s11=Gv[5]+rdv[d0+1];
        float s22=Gv[10]+rdv[d0+2], s33=Gv[15]+rdv[d0+3];
        float v0_=yv[d0]-cm[0], v1_=yv[d0+1]-cm[1], v2_=yv[d0+2]-cm[2], v3_=yv[d0+3]-cm[3];

        float L00=sqrtf(s00), rr0=1.f/L00;
        float L10=G10*rr0, L20=G20*rr0, L30=G30*rr0;
        float L11=sqrtf(s11-L10*L10), rr1=1.f/L11;
        float L21=(G21-L20*L10)*rr1, L31=(G31-L30*L10)*rr1;
        float L22=sqrtf(s22-L20*L20-L21*L21), rr2=1.f/L22;
        float L32=(G32-L30*L20-L31*L21)*rr2;
        float L33=sqrtf(s33-L30*L30-L31*L31-L32*L32), rr3=1.f/L33;
        llacc += 2.f*logf(L00*L11*L22*L33);

        float m00=rr0, m11=rr1, m22=rr2, m33=rr3;
        float m10=-rr1*(L10*m00);
        float m20=-rr2*(L20*m00+L21*m10);
        float m21=-rr2*(L21*m11);
        float m30=-rr3*(L30*m00+L31*m10+L32*m20);
        float m31=-rr3*(L31*m11+L32*m21);
        float m32=-rr3*(L32*m22);

        float si00=m00*m00+m10*m10+m20*m20+m30*m30;
        float si01=m10*m11+m20*m21+m30*m31;
        float si02=m20*m22+m30*m32;
        float si03=m30*m33;
        float si11=m11*m11+m21*m21+m31*m31;
        float si12=m21*m22+m31*m32;
        float si13=m31*m33;
        float si22=m22*m22+m32*m32;
        float si23=m32*m33;
        float si33=m33*m33;

        float uu0=si00*v0_+si01*v1_+si02*v2_+si03*v3_;
        float uu1=si01*v0_+si11*v1_+si12*v2_+si13*v3_;
        float uu2=si02*v0_+si12*v1_+si22*v2_+si23*v3_;
        float uu3=si03*v0_+si13*v1_+si23*v2_+si33*v3_;
        llacc += v0_*uu0 + v1_*uu1 + v2_*uu2 + v3_*uu3;

        float wr0=wvv[0], wr1=wvv[1], wr2=wvv[2], wr3=wvv[3];
        float zr0=wr0*si00+wr1*si01+wr2*si02+wr3*si03;
        float zr1=wr0*si01+wr1*si11+wr2*si12+wr3*si13;
        float zr2=wr0*si02+wr1*si12+wr2*si22+wr3*si23;
        float zr3=wr0*si03+wr1*si13+wr2*si23+wr3*si33;

        #pragma unroll
        for (int u = 0; u < 4; ++u) {
          int gb = gq*16 + u*4;
          Preg[u].x -= zr0*WL[(gb+0)*5+0]+zr1*WL[(gb+0)*5+1]+zr2*WL[(gb+0)*5+2]+zr3*WL[(gb+0)*5+3];
          Preg[u].y -= zr0*WL[(gb+1)*5+0]+zr1*WL[(gb+1)*5+1]+zr2*WL[(gb+1)*5+2]+zr3*WL[(gb+1)*5+3];
          Preg[u].z -= zr0*WL[(gb+2)*5+0]+zr1*WL[(gb+2)*5+1]+zr2*WL[(gb+2)*5+2]+zr3*WL[(gb+2)*5+3];
          Preg[u].w -= zr0*WL[(gb+3)*5+0]+zr1*WL[(gb+3)*5+1]+zr2*WL[(gb+3)*5+2]+zr3*WL[(gb+3)*5+3];
        }
        mu_h += wr0*uu0 + wr1*uu1 + wr2*uu2 + wr3*uu3;
        if (gq == 0) muL[h] = mu_h;
      }
      __syncthreads();
    }
    float lw_j = base_lw - 0.5f * (OB * LOG2PI + llacc);

    // ---- write state (coherent): PPbf16 = 0.5(P+P^T) + mu mu^T ; mu ; lw ----
    #pragma unroll
    for (int u = 0; u < 4; ++u) *(float4*)&Pm[h*68 + gq*16 + 4*u] = Preg[u];
    __syncthreads();
    {
      unsigned* lwW = (unsigned*)(ws + ((t & 1) ? WS_LW1 : WS_LW0));
      unsigned* muW = (unsigned*)(ws + ((t & 1) ? WS_MU1 : WS_MU0));
      ull* ppW = (ull*)(ppb + ((t & 1) ? 131072u : 0u)) + (size_t)j*1024 + tid*4;
      float mh = muL[h];
      unsigned pk[8];
      #pragma unroll
      for (int u = 0; u < 4; ++u) {
        int gb = gq*16 + 4*u;
        float4 pv = Preg[u];
        float4 pt = make_float4(Pm[(gb+0)*68 + h], Pm[(gb+1)*68 + h],
                                Pm[(gb+2)*68 + h], Pm[(gb+3)*68 + h]);
        float4 m4 = *(const float4*)&muL[gb];
        float ox = 0.5f*(pv.x + pt.x) + mh*m4.x;
        float oy = 0.5f*(pv.y + pt.y) + mh*m4.y;
        float oz = 0.5f*(pv.z + pt.z) + mh*m4.z;
        float ow = 0.5f*(pv.w + pt.w) + mh*m4.w;
        pk[u*2]   = packbf(ox, oy);
        pk[u*2+1] = packbf(oz, ow);
      }
      ast64(ppW+0, (ull)pk[0] | ((ull)pk[1] << 32));
      ast64(ppW+1, (ull)pk[2] | ((ull)pk[3] << 32));
      ast64(ppW+2, (ull)pk[4] | ((ull)pk[5] << 32));
      ast64(ppW+3, (ull)pk[6] | ((ull)pk[7] << 32));
      if (gq == 0) ast32(&muW[j*64 + h], __float_as_uint(mu_h));
      if (tid == 0) ast32(&lwW[j], __float_as_uint(lw_j));
    }
    asm volatile("s_waitcnt vmcnt(0)" ::: "memory");
    __syncthreads();
    if (tid == 0) ast32(&flags[j], (unsigned)(t + 1));
  }

  // ---- final logsumexp over components (block 0) ----
  if (j == 0) {
    if (tid < 32) {
      while (ald32(&flags[tid]) < (unsigned)TLEN) __builtin_amdgcn_s_sleep(1);
    }
    __syncthreads();
    if (tid == 0) {
      const unsigned* lw = (const unsigned*)(ws + (((TLEN - 1) & 1) ? WS_LW1 : WS_LW0));
      float mx = -1e30f;
      float v[KC];
      for (int k = 0; k < KC; ++k) { v[k] = __uint_as_float(ald32(lw + k)); mx = fmaxf(mx, v[k]); }
      float s = 0.f;
      for (int k = 0; k < KC; ++k) s += expf(v[k] - mx);
      gout[0] = mx + logf(s);
    }
  }
}

extern "C" void kernel_launch(void* const* d_in, const int* in_sizes, int n_in,
                              void* d_out, int out_size, void* d_ws, size_t ws_size,
                              hipStream_t stream) {
  const float* gdata = (const float*)d_in[0];
  const float* gtl   = (const float*)d_in[1];
  const float* gA    = (const float*)d_in[2];
  const float* gltn  = (const float*)d_in[3];
  const float* gC    = (const float*)d_in[4];
  const float* glon  = (const float*)d_in[5];
  float* ws = (float*)d_ws;

  hipMemsetAsync(d_ws, 0, 256, stream);
  hipLaunchKernelGGL(slds_kernel, dim3(NB), dim3(NT), 0, stream,
                     gdata, gtl, gA, gltn, gC, glon, (float*)d_out, ws);
}